// Round 1
// 130.317 us; speedup vs baseline: 1.0030x; 1.0030x over previous
//
#include <hip/hip_runtime.h>
#include <math.h>

// GaussianCircular: separable 15x15 Gaussian conv, fp32, SAME zero-pad.
// R6: BATCH-VERTICAL, single barrier. R5's ring structure issued ONE load per
// row-iteration and immediately consumed it (s_waitcnt vmcnt(0)) and hit a
// barrier (which also drains vmcnt) -> steady-state MLP ~= 1 load/wave ->
// 2.9 TB/s (46% of achievable) while traffic was already ideal (latency-bound).
// Here each thread issues ALL 30 input-row float4 loads back-to-back (30 in
// flight per wave), vertical-convolves into 16 register accumulators, writes
// 16 mid rows to LDS, takes ONE __syncthreads (vs 16), then does the
// horizontal pass + stores. Same FP accumulation order as R5 -> same output.
// LDS 66.5 KB -> 2 blocks/CU (8 waves/CU); VGPRs up to 256 are therefore free:
// __launch_bounds__(256,2) tells the allocator to target that point (R4's
// lesson: high min-waves forces VGPR=64 -> spills; 2 matches the LDS cap).

#define RAD   7
#define KS    15
#define S     16               // output rows per strip
#define NIN   (S + 2 * RAD)    // 30 input rows per strip
#define PADW  8                // zero pad words each side of mid row
#define MIDW  (1024 + 2 * PADW)

using f32x4 = __attribute__((ext_vector_type(4))) float;

__global__ __launch_bounds__(256, 2) void gauss_batchv_kernel(
    const float* __restrict__ x,
    const float* __restrict__ sigma_p,
    const float* __restrict__ gain_p,
    float* __restrict__ out,
    int H, int W)
{
    __shared__ float smid[S][MIDW];          // 16 x 1040 fp32 = 66,560 B

    const int strips = H / S;                // 64
    const int n      = blockIdx.x / strips;
    const int strip  = blockIdx.x - n * strips;
    const int row0   = strip * S;

    const int tid = threadIdx.x;
    const int c0  = tid * 4;                 // 256 thr * 4 = 1024 = W

    const float* __restrict__ img    = x   + (size_t)n * H * W;
    float*       __restrict__ outimg = out + (size_t)n * H * W;

    // Separable weights: gain*exp(-(i^2+j^2)/2s^2) = gain * w[i] * w[j]
    const float s    = fabsf(sigma_p[0]);
    const float gain = gain_p[0];
    const float inv  = -1.0f / (2.0f * s * s);
    float w[KS];
#pragma unroll
    for (int j = 0; j < KS; ++j) {
        const float d = (float)(j - RAD);
        w[j] = expf(d * d * inv);
    }

    // Zero the 16 pad words of each of the 16 mid rows: one word per thread.
    // (word pw<8 -> left pad [0..7]; else right pad [1032..1039] = 1024+pw)
    {
        const int o    = tid >> 4;           // 0..15: row
        const int pw   = tid & 15;           // 0..15: pad word
        const int word = (pw < 8) ? pw : (1024 + pw);
        smid[o][word] = 0.0f;
    }

    // ---- phase 1a: issue ALL 30 input-row loads (max MLP, no barriers) ----
    float4 vin[NIN];
#pragma unroll
    for (int p = 0; p < NIN; ++p) {
        const int gr  = row0 - RAD + p;
        const int grc = min(max(gr, 0), H - 1);   // clamped row (coalesced)
        vin[p] = *(const float4*)(img + (size_t)grc * W + c0);
    }

    // ---- phase 1b: vertical conv into 16 register accumulators ----
    float4 acc[S];
#pragma unroll
    for (int o = 0; o < S; ++o) acc[o] = make_float4(0.f, 0.f, 0.f, 0.f);

#pragma unroll
    for (int p = 0; p < NIN; ++p) {
        const int gr = row0 - RAD + p;
        const float m = (gr >= 0 && gr < H) ? 1.0f : 0.0f;  // zero-pad mask
        float4 v = vin[p];
        v.x *= m; v.y *= m; v.z *= m; v.w *= m;
        // output row o uses input row p iff 0 <= p-o <= 14; weight w[p-o]
#pragma unroll
        for (int o = 0; o < S; ++o) {
            if (o >= p - (KS - 1) && o <= p) {   // compile-time after unroll
                const float wv = w[p - o];
                acc[o].x += wv * v.x;
                acc[o].y += wv * v.y;
                acc[o].z += wv * v.z;
                acc[o].w += wv * v.w;
            }
        }
    }

    // ---- hand all 16 mid rows across lanes through LDS, ONE barrier ----
#pragma unroll
    for (int o = 0; o < S; ++o)
        *(float4*)&smid[o][PADW + c0] = acc[o];
    __syncthreads();

    // ---- phase 2: horizontal pass per row, 5 aligned b128 LDS reads ----
#pragma unroll
    for (int o = 0; o < S; ++o) {
        const float* mp = &smid[o][c0];          // word c0 = col c0-8
        const float4 f0 = *(const float4*)(mp);
        const float4 f1 = *(const float4*)(mp + 4);
        const float4 f2 = *(const float4*)(mp + 8);
        const float4 f3 = *(const float4*)(mp + 12);
        const float4 f4 = *(const float4*)(mp + 16);
        float f[20] = { f0.x, f0.y, f0.z, f0.w,
                        f1.x, f1.y, f1.z, f1.w,
                        f2.x, f2.y, f2.z, f2.w,
                        f3.x, f3.y, f3.z, f3.w,
                        f4.x, f4.y, f4.z, f4.w };
        float4 a = make_float4(0.f, 0.f, 0.f, 0.f);
#pragma unroll
        for (int jj = 0; jj < KS; ++jj) {
            const float wv = w[jj];
            a.x += wv * f[1 + jj];
            a.y += wv * f[2 + jj];
            a.z += wv * f[3 + jj];
            a.w += wv * f[4 + jj];
        }
        a.x *= gain; a.y *= gain; a.z *= gain; a.w *= gain;

        float* op = outimg + (size_t)(row0 + o) * W + c0;
        __builtin_nontemporal_store(*(const f32x4*)&a, (f32x4*)op);
    }
}

extern "C" void kernel_launch(void* const* d_in, const int* in_sizes, int n_in,
                              void* d_out, int out_size, void* d_ws, size_t ws_size,
                              hipStream_t stream) {
    const float* x       = (const float*)d_in[0];
    const float* sigma_p = (const float*)d_in[1];
    const float* gain_p  = (const float*)d_in[2];
    float* out = (float*)d_out;

    const int H = 1024, W = 1024;
    const int N = in_sizes[0] / (H * W);               // 16

    const dim3 grid(N * (H / S));                      // 16 * 64 = 1024 blocks
    gauss_batchv_kernel<<<grid, 256, 0, stream>>>(x, sigma_p, gain_p, out, H, W);
}